// Round 3
// baseline (277.237 us; speedup 1.0000x reference)
//
#include <hip/hip_runtime.h>
#include <math.h>
#include <float.h>

#define BS 256
typedef unsigned long long u64;

// ws layout (N = 262144, NB = N/256 = 1024):
//   [0,32)                  double sums[4] (lp, la, lw, ls)
//   [32,36)                 int done
//   [64, 64+4096)           int blockSums[NB]
//   [64+4096, 64+8192)      int blockOffsets[NB]
//   [8256, 8256+4N)         int rowStart[N]
//   [8256+4N, +8N more)     u64 best[N]   (packed (dist_bits<<32)|row)

__global__ void block_sum_kernel(const int* __restrict__ counts,
                                 int* __restrict__ blockSums, int N) {
    int i = blockIdx.x * BS + threadIdx.x;
    int v = (i < N) ? counts[i] : 0;
    for (int o = 32; o > 0; o >>= 1) v += __shfl_down(v, o, 64);
    __shared__ int ws[BS / 64];
    int lane = threadIdx.x & 63, w = threadIdx.x >> 6;
    if (lane == 0) ws[w] = v;
    __syncthreads();
    if (threadIdx.x == 0) {
        int s = 0;
        for (int ww = 0; ww < BS / 64; ++ww) s += ws[ww];
        blockSums[blockIdx.x] = s;
    }
}

// Exclusive scan of up to 1024 block sums (single block) + zero accumulators.
__global__ void scan_kernel(const int* __restrict__ blockSums,
                            int* __restrict__ blockOffsets, int nb,
                            double* __restrict__ sums, int* __restrict__ done) {
    __shared__ int tmp[1024];
    int t = threadIdx.x;
    if (t < 4) sums[t] = 0.0;
    if (t == 4) *done = 0;
    int v = (t < nb) ? blockSums[t] : 0;
    tmp[t] = v;
    __syncthreads();
    for (int off = 1; off < 1024; off <<= 1) {
        int x = (t >= off) ? tmp[t - off] : 0;
        __syncthreads();
        tmp[t] += x;
        __syncthreads();
    }
    if (t < nb) blockOffsets[t] = tmp[t] - v;  // inclusive -> exclusive
}

// rowStart[i] = global exclusive prefix of counts; best[i] = ~0
__global__ void row_start_kernel(const int* __restrict__ counts,
                                 const int* __restrict__ blockOffsets,
                                 int* __restrict__ rowStart,
                                 u64* __restrict__ best, int N) {
    const int t = threadIdx.x;
    const int i = blockIdx.x * BS + t;
    const int lane = t & 63, w = t >> 6;
    int c = (i < N) ? counts[i] : 0;
    int incl = c;
    for (int o = 1; o < 64; o <<= 1) {
        int x = __shfl_up(incl, o, 64);
        if (lane >= o) incl += x;
    }
    __shared__ int waveTot[BS / 64];
    if (lane == 63) waveTot[w] = incl;
    __syncthreads();
    int base = blockOffsets[blockIdx.x];
    for (int ww = 0; ww < w; ++ww) base += waveTot[ww];
    if (i < N) {
        rowStart[i] = base + incl - c;
        best[i] = ~0ULL;
    }
}

// Phase 1: one thread per gt row (coalesced). Segmented wave-min + atomicMin.
__global__ void seg_min_kernel(const float* __restrict__ pred,
                               const float* __restrict__ gt,
                               const int* __restrict__ rowStart,
                               u64* __restrict__ best, int N, int M) {
    const int j = blockIdx.x * BS + threadIdx.x;
    const int lane = threadIdx.x & 63;
    int seg = -1;
    u64 key = ~0ULL;
    if (j < M) {
        // upper_bound: first s with rowStart[s] > j, owner = that - 1
        int lo = 0, hi = N;
        while (lo < hi) {
            int mid = (lo + hi) >> 1;
            if (rowStart[mid] <= j) lo = mid + 1; else hi = mid;
        }
        seg = lo - 1;
        const float2 g = *reinterpret_cast<const float2*>(gt + (size_t)j * 6);
        const float2 p = *reinterpret_cast<const float2*>(pred + (size_t)seg * 6);
        const float dx = p.x - g.x, dy = p.y - g.y;
        const float d2 = dx * dx + dy * dy;  // >= 0, IEEE bits monotone
        key = ((u64)__float_as_uint(d2) << 32) | (unsigned int)j;
    }
    // segmented min toward run head (segs non-decreasing across lanes)
    for (int o = 1; o <= 32; o <<= 1) {
        int s2 = __shfl_down(seg, o, 64);
        u64 k2 = __shfl_down(key, o, 64);
        if (lane + o < 64 && s2 == seg && k2 < key) key = k2;
    }
    int segPrev = __shfl_up(seg, 1, 64);
    bool head = (lane == 0) || (segPrev != seg);
    if (j < M && head) atomicMin(&best[seg], key);
}

// Phase 2: one thread per pred row. Losses + reduction + fused finalize.
__global__ void loss_kernel(const float* __restrict__ pred,
                            const float* __restrict__ gt,
                            const int* __restrict__ counts,
                            const u64* __restrict__ best,
                            double* __restrict__ sums, int* __restrict__ done,
                            float* __restrict__ out, int N, int numBlocks) {
    const int t = threadIdx.x;
    const int i = blockIdx.x * BS + t;
    const int lane = t & 63, w = t >> 6;

    float lp = 0.f, la = 0.f, lw = 0.f, ls = 0.f;
    if (i < N && counts[i] > 0) {
        const u64 key = best[i];
        const float d2 = __uint_as_float((unsigned int)(key >> 32));
        const int bj = (int)(key & 0xffffffffu);
        lp = 1.0f - expf(-d2 / 0.045f);  // max resp == exp(-min d2 / (2 s^2))

        const float* p = pred + (size_t)i * 6;
        const float2 p23 = *reinterpret_cast<const float2*>(p + 2);
        const float2 p45 = *reinterpret_cast<const float2*>(p + 4);
        const float* ng = gt + (size_t)bj * 6;
        const float2 g23 = *reinterpret_cast<const float2*>(ng + 2);
        const float2 g45 = *reinterpret_cast<const float2*>(ng + 4);

        la = fabsf(p23.x - g23.x) + fabsf(p23.y - g23.y);
        const float d = p45.x - g45.x;
        const float ad = fabsf(d);
        lw = (ad < 1.0f) ? 0.5f * d * d : ad - 0.5f;
        const float x = p45.y;
        if (g45.y > 0.0f) {
            ls = fmaxf(x, 0.0f) - x * g45.y + log1pf(expf(-fabsf(x)));
        }
    }

    for (int o = 32; o > 0; o >>= 1) {
        lp += __shfl_down(lp, o, 64);
        la += __shfl_down(la, o, 64);
        lw += __shfl_down(lw, o, 64);
        ls += __shfl_down(ls, o, 64);
    }
    __shared__ float red[BS / 64][4];
    if (lane == 0) { red[w][0] = lp; red[w][1] = la; red[w][2] = lw; red[w][3] = ls; }
    __syncthreads();
    if (t == 0) {
        double s0 = 0, s1 = 0, s2 = 0, s3 = 0;
        for (int ww = 0; ww < BS / 64; ++ww) {
            s0 += (double)red[ww][0];
            s1 += (double)red[ww][1];
            s2 += (double)red[ww][2];
            s3 += (double)red[ww][3];
        }
        atomicAdd(&sums[0], s0);
        atomicAdd(&sums[1], s1);
        atomicAdd(&sums[2], s2);
        atomicAdd(&sums[3], s3);
        __threadfence();
        int prev = atomicAdd(done, 1);
        if (prev == numBlocks - 1) {
            const double t0 = atomicAdd(&sums[0], 0.0);
            const double t1 = atomicAdd(&sums[1], 0.0);
            const double t2 = atomicAdd(&sums[2], 0.0);
            const double t3 = atomicAdd(&sums[3], 0.0);
            const double inv = 1.0 / (double)N;
            const float flp = (float)(t0 * inv);
            const float fla = (float)(t1 * inv);
            const float flw = (float)(t2 * inv);
            const float fls = (float)(t3 * inv);
            out[0] = flp;
            out[1] = fla;
            out[2] = flw;
            out[3] = fls;
            out[4] = flp + fla + flw + 0.5f * fls;
        }
    }
}

extern "C" void kernel_launch(void* const* d_in, const int* in_sizes, int n_in,
                              void* d_out, int out_size, void* d_ws, size_t ws_size,
                              hipStream_t stream) {
    const float* pred = (const float*)d_in[0];
    const float* gt = (const float*)d_in[1];
    const int* counts = (const int*)d_in[2];
    float* out = (float*)d_out;

    const int N = in_sizes[2];
    const int M = in_sizes[1] / 6;
    const int numBlocks = (N + BS - 1) / BS;   // 1024
    const int rowBlocks = (M + BS - 1) / BS;

    double* sums = (double*)d_ws;
    int* done = (int*)((char*)d_ws + 32);
    int* blockSums = (int*)((char*)d_ws + 64);
    int* blockOffsets = (int*)((char*)d_ws + 64 + 4096);
    int* rowStart = (int*)((char*)d_ws + 64 + 8192);
    u64* best = (u64*)((char*)d_ws + 64 + 8192 + (size_t)N * 4);

    block_sum_kernel<<<numBlocks, BS, 0, stream>>>(counts, blockSums, N);
    scan_kernel<<<1, 1024, 0, stream>>>(blockSums, blockOffsets, numBlocks, sums, done);
    row_start_kernel<<<numBlocks, BS, 0, stream>>>(counts, blockOffsets, rowStart, best, N);
    seg_min_kernel<<<rowBlocks, BS, 0, stream>>>(pred, gt, rowStart, best, N, M);
    loss_kernel<<<numBlocks, BS, 0, stream>>>(pred, gt, counts, best,
                                              sums, done, out, N, numBlocks);
}

// Round 4
// 220.035 us; speedup vs baseline: 1.2600x; 1.2600x over previous
//
#include <hip/hip_runtime.h>
#include <math.h>
#include <float.h>

#define BS 256
typedef unsigned long long u64;

// ws layout:
//   [0,32)               double sums[4] (lp, la, lw, ls)
//   [32,36)              int done
//   [64, 64+4*nb)        int blockSums[nb]
//   [64+4*nb, 64+8*nb)   int blockOffsets[nb]

__global__ void block_sum_kernel(const int* __restrict__ counts,
                                 int* __restrict__ blockSums, int N) {
    int i = blockIdx.x * BS + threadIdx.x;
    int v = (i < N) ? counts[i] : 0;
    for (int o = 32; o > 0; o >>= 1) v += __shfl_down(v, o, 64);
    __shared__ int ws[BS / 64];
    int lane = threadIdx.x & 63, w = threadIdx.x >> 6;
    if (lane == 0) ws[w] = v;
    __syncthreads();
    if (threadIdx.x == 0) {
        int s = 0;
        for (int ww = 0; ww < BS / 64; ++ww) s += ws[ww];
        blockSums[blockIdx.x] = s;
    }
}

// Exclusive scan of up to 1024 block sums (single block) + zero accumulators.
__global__ void scan_kernel(const int* __restrict__ blockSums,
                            int* __restrict__ blockOffsets, int nb,
                            double* __restrict__ sums, int* __restrict__ done) {
    __shared__ int tmp[1024];
    int t = threadIdx.x;
    if (t < 4) sums[t] = 0.0;
    if (t == 4) *done = 0;
    int v = (t < nb) ? blockSums[t] : 0;
    tmp[t] = v;
    __syncthreads();
    for (int off = 1; off < 1024; off <<= 1) {
        int x = (t >= off) ? tmp[t - off] : 0;
        __syncthreads();
        tmp[t] += x;
        __syncthreads();
    }
    if (t < nb) blockOffsets[t] = tmp[t] - v;  // inclusive -> exclusive
}

// Fused: block b owns pred rows [b*256, b*256+256) and their contiguous gt
// range. All segment lookup / argmin state lives in LDS.
__global__ void fused_kernel(const float* __restrict__ pred,
                             const float* __restrict__ gt,
                             const int* __restrict__ counts,
                             const int* __restrict__ blockOffsets,
                             double* __restrict__ sums, int* __restrict__ done,
                             float* __restrict__ out, int N, int numBlocks) {
    const int t = threadIdx.x;
    const int b = blockIdx.x;
    const int i = b * BS + t;
    const int lane = t & 63, w = t >> 6;

    __shared__ int segStart[BS + 1];   // local exclusive prefix of counts
    __shared__ u64 bestLds[BS];        // (d2_bits<<32)|global_row per pred row
    __shared__ float px[BS], py[BS];
    __shared__ int waveTot[BS / 64];
    __shared__ float red[BS / 64][4];

    const int c = (i < N) ? counts[i] : 0;
    int incl = c;
    for (int o = 1; o < 64; o <<= 1) {
        int x = __shfl_up(incl, o, 64);
        if (lane >= o) incl += x;
    }
    if (lane == 63) waveTot[w] = incl;
    __syncthreads();
    int wbase = 0;
    for (int ww = 0; ww < w; ++ww) wbase += waveTot[ww];
    const int localStart = wbase + incl - c;
    segStart[t] = localStart;
    if (t == BS - 1) segStart[BS] = localStart + c;  // block total
    bestLds[t] = ~0ULL;
    if (i < N) {
        const float2 p = *reinterpret_cast<const float2*>(pred + (size_t)i * 6);
        px[t] = p.x; py[t] = p.y;
    }
    __syncthreads();

    const int base = blockOffsets[b];
    const int blockTotal = segStart[BS];

    for (int tile = 0; tile < blockTotal; tile += BS) {
        const int j = tile + t;  // local gt index
        int owner = -1;
        u64 key = ~0ULL;
        if (j < blockTotal) {
            const float2 g = *reinterpret_cast<const float2*>(gt + (size_t)(base + j) * 6);
            // first s in [1,BS] with segStart[s] > j  (segStart[BS] > j always)
            int lo = 1, hi = BS;
            while (lo < hi) {
                const int mid = (lo + hi) >> 1;
                if (segStart[mid] <= j) lo = mid + 1; else hi = mid;
            }
            owner = lo - 1;
            const float dx = px[owner] - g.x, dy = py[owner] - g.y;
            const float d2 = dx * dx + dy * dy;  // >=0; IEEE bits monotone
            key = ((u64)__float_as_uint(d2) << 32) | (unsigned int)(base + j);
        }
        // wave-segmented min toward run head (owner non-decreasing in lane)
        for (int o = 1; o <= 32; o <<= 1) {
            const int o2 = __shfl_down(owner, o, 64);
            const u64 k2 = __shfl_down(key, o, 64);
            if (lane + o < 64 && o2 == owner && k2 < key) key = k2;
        }
        const int ownerPrev = __shfl_up(owner, 1, 64);
        const bool head = (lane == 0) || (ownerPrev != owner);
        if (j < blockTotal && head) atomicMin(&bestLds[owner], key);
    }
    __syncthreads();

    float lp = 0.f, la = 0.f, lw = 0.f, ls = 0.f;
    if (i < N && c > 0) {
        const u64 key = bestLds[t];
        const float d2 = __uint_as_float((unsigned int)(key >> 32));
        const int bj = (int)(key & 0xffffffffu);
        lp = 1.0f - expf(-d2 / 0.045f);  // max resp == exp(-min d2/(2*sigma^2))

        const float* p = pred + (size_t)i * 6;
        const float2 p23 = *reinterpret_cast<const float2*>(p + 2);
        const float2 p45 = *reinterpret_cast<const float2*>(p + 4);
        const float* ng = gt + (size_t)bj * 6;
        const float2 g23 = *reinterpret_cast<const float2*>(ng + 2);
        const float2 g45 = *reinterpret_cast<const float2*>(ng + 4);

        la = fabsf(p23.x - g23.x) + fabsf(p23.y - g23.y);
        const float d = p45.x - g45.x;
        const float ad = fabsf(d);
        lw = (ad < 1.0f) ? 0.5f * d * d : ad - 0.5f;
        const float x = p45.y;
        if (g45.y > 0.0f) {
            ls = fmaxf(x, 0.0f) - x * g45.y + log1pf(expf(-fabsf(x)));
        }
    }

    for (int o = 32; o > 0; o >>= 1) {
        lp += __shfl_down(lp, o, 64);
        la += __shfl_down(la, o, 64);
        lw += __shfl_down(lw, o, 64);
        ls += __shfl_down(ls, o, 64);
    }
    if (lane == 0) { red[w][0] = lp; red[w][1] = la; red[w][2] = lw; red[w][3] = ls; }
    __syncthreads();
    if (t == 0) {
        double s0 = 0, s1 = 0, s2 = 0, s3 = 0;
        for (int ww = 0; ww < BS / 64; ++ww) {
            s0 += (double)red[ww][0];
            s1 += (double)red[ww][1];
            s2 += (double)red[ww][2];
            s3 += (double)red[ww][3];
        }
        atomicAdd(&sums[0], s0);
        atomicAdd(&sums[1], s1);
        atomicAdd(&sums[2], s2);
        atomicAdd(&sums[3], s3);
        __threadfence();
        const int prev = atomicAdd(done, 1);
        if (prev == numBlocks - 1) {
            const double t0 = atomicAdd(&sums[0], 0.0);
            const double t1 = atomicAdd(&sums[1], 0.0);
            const double t2 = atomicAdd(&sums[2], 0.0);
            const double t3 = atomicAdd(&sums[3], 0.0);
            const double inv = 1.0 / (double)N;
            const float flp = (float)(t0 * inv);
            const float fla = (float)(t1 * inv);
            const float flw = (float)(t2 * inv);
            const float fls = (float)(t3 * inv);
            out[0] = flp;
            out[1] = fla;
            out[2] = flw;
            out[3] = fls;
            out[4] = flp + fla + flw + 0.5f * fls;
        }
    }
}

extern "C" void kernel_launch(void* const* d_in, const int* in_sizes, int n_in,
                              void* d_out, int out_size, void* d_ws, size_t ws_size,
                              hipStream_t stream) {
    const float* pred = (const float*)d_in[0];
    const float* gt = (const float*)d_in[1];
    const int* counts = (const int*)d_in[2];
    float* out = (float*)d_out;

    const int N = in_sizes[2];
    const int numBlocks = (N + BS - 1) / BS;  // 1024

    double* sums = (double*)d_ws;
    int* done = (int*)((char*)d_ws + 32);
    int* blockSums = (int*)((char*)d_ws + 64);
    int* blockOffsets = blockSums + numBlocks;

    block_sum_kernel<<<numBlocks, BS, 0, stream>>>(counts, blockSums, N);
    scan_kernel<<<1, 1024, 0, stream>>>(blockSums, blockOffsets, numBlocks, sums, done);
    fused_kernel<<<numBlocks, BS, 0, stream>>>(pred, gt, counts, blockOffsets,
                                               sums, done, out, N, numBlocks);
}